// Round 6
// baseline (487.072 us; speedup 1.0000x reference)
//
#include <hip/hip_runtime.h>
#include <hip/hip_bf16.h>

// ObjectAttentionBlock on MI355X, round 6: single mega-kernel.
// The whole chain is pixel-local per 128-pixel slice; fusing G1..G_up into one
// kernel removes q1/q2/ctxT HBM round-trips (402 MB) and 4 launch/tails.
// LDS 128KB: [q1s 64K | q2s 64K]; xs(32K f32 x-stage) aliases q2s, P(40K)
// aliases q1s, ctx aliases q2s. XOR swizzle byte^((row&7)<<4) on both sides.

typedef __bf16 bf16x8 __attribute__((ext_vector_type(8)));
typedef float f32x4 __attribute__((ext_vector_type(4)));

#define AS1 __attribute__((address_space(1)))
#define AS3 __attribute__((address_space(3)))
#define MFMA_16x16x32(a, b, c) __builtin_amdgcn_mfma_f32_16x16x32_bf16((a), (b), (c), 0, 0, 0)

__device__ __forceinline__ unsigned short f2bf(float f) {
  union { float f; unsigned u; } x; x.f = f;
  unsigned r = (x.u + 0x7FFFu + ((x.u >> 16) & 1u)) >> 16;  // RNE
  return (unsigned short)r;
}

// ---------------- merged weight cast ----------------
__global__ __launch_bounds__(256) void cast_weights(
    const float* __restrict__ w1, const float* __restrict__ w2,
    const float* __restrict__ wu, unsigned short* __restrict__ W1b,
    unsigned short* __restrict__ W2b, unsigned short* __restrict__ Wub) {
  int i = blockIdx.x * 256 + threadIdx.x;   // grid 1280 -> 327680 items
  if (i < 131072) W1b[i] = f2bf(w1[i]);
  else if (i < 196608) W2b[i - 131072] = f2bf(w2[i - 131072]);
  else if (i < 327680) Wub[i - 196608] = f2bf(wu[i - 196608]);
}

// ---------------- key/value kernel (fp32 math, tiny) ----------------
__global__ __launch_bounds__(256) void kv_kernel(
    const float* __restrict__ proxy,
    const float* __restrict__ w_fo1, const float* __restrict__ b_fo1,
    const float* __restrict__ w_fo2, const float* __restrict__ b_fo2,
    const float* __restrict__ w_fd, const float* __restrict__ b_fd,
    unsigned short* __restrict__ keyT, unsigned short* __restrict__ Vv) {
  __shared__ float cols[512][8];
  __shared__ float k1s[256][8];
  const int b = blockIdx.y;
  const int p0 = blockIdx.x * 8;      // 20 chunks cover p 0..159
  const int t = threadIdx.x;
#pragma unroll
  for (int i = 0; i < 8; i++) {
    int idx = t + i * 256;
    int c = idx >> 2, q = idx & 3;
    int p = p0 + q * 2;
    float2 v = make_float2(0.f, 0.f);
    if (p < 150) v = *(const float2*)(proxy + ((size_t)b * 512 + c) * 150 + p);
    cols[c][q * 2 + 0] = v.x;
    cols[c][q * 2 + 1] = v.y;
  }
  __syncthreads();
  float accV[8], accK[8];
  {
    float bv = b_fd[t], bk = b_fo1[t];
#pragma unroll
    for (int px = 0; px < 8; px++) { accV[px] = bv; accK[px] = bk; }
  }
#define KV_FMA(j, wv_, wk_)                                      \
  { float4 ca = *(const float4*)&cols[c + j][0];                 \
    float4 cb = *(const float4*)&cols[c + j][4];                 \
    accV[0] += wv_ * ca.x; accV[1] += wv_ * ca.y;                \
    accV[2] += wv_ * ca.z; accV[3] += wv_ * ca.w;                \
    accV[4] += wv_ * cb.x; accV[5] += wv_ * cb.y;                \
    accV[6] += wv_ * cb.z; accV[7] += wv_ * cb.w;                \
    accK[0] += wk_ * ca.x; accK[1] += wk_ * ca.y;                \
    accK[2] += wk_ * ca.z; accK[3] += wk_ * ca.w;                \
    accK[4] += wk_ * cb.x; accK[5] += wk_ * cb.y;                \
    accK[6] += wk_ * cb.z; accK[7] += wk_ * cb.w; }
  for (int c = 0; c < 512; c += 4) {
    float4 wv4 = *(const float4*)(w_fd + (size_t)t * 512 + c);
    float4 wk4 = *(const float4*)(w_fo1 + (size_t)t * 512 + c);
    KV_FMA(0, wv4.x, wk4.x)
    KV_FMA(1, wv4.y, wk4.y)
    KV_FMA(2, wv4.z, wk4.z)
    KV_FMA(3, wv4.w, wk4.w)
  }
#pragma unroll
  for (int px = 0; px < 8; px++) {
    Vv[((size_t)b * 256 + t) * 160 + p0 + px] = f2bf(fmaxf(accV[px], 0.f));
    k1s[t][px] = fmaxf(accK[px], 0.f);
  }
  __syncthreads();
  float accY[8];
  {
    float by = b_fo2[t];
#pragma unroll
    for (int px = 0; px < 8; px++) accY[px] = by;
  }
#define KV_FMA2(j, wy_)                                          \
  { float4 ca = *(const float4*)&k1s[c + j][0];                  \
    float4 cb = *(const float4*)&k1s[c + j][4];                  \
    accY[0] += wy_ * ca.x; accY[1] += wy_ * ca.y;                \
    accY[2] += wy_ * ca.z; accY[3] += wy_ * ca.w;                \
    accY[4] += wy_ * cb.x; accY[5] += wy_ * cb.y;                \
    accY[6] += wy_ * cb.z; accY[7] += wy_ * cb.w; }
  for (int c = 0; c < 256; c += 4) {
    float4 wy4 = *(const float4*)(w_fo2 + (size_t)t * 256 + c);
    KV_FMA2(0, wy4.x)
    KV_FMA2(1, wy4.y)
    KV_FMA2(2, wy4.z)
    KV_FMA2(3, wy4.w)
  }
#pragma unroll
  for (int px = 0; px < 8; px++)
    keyT[((size_t)b * 160 + p0 + px) * 256 + t] = f2bf(fmaxf(accY[px], 0.f));
}

// ---------------- mega kernel: all pixel-local phases fused ----------------
// Per block: 128 pixels, 8 waves. Phases:
//  1) q1 = relu(x^T W1^T + b1)       (x staged f32 via swizzled-source gload_lds)
//  2) q2 = relu(q1 W2^T + b2)
//  3) S = q2 Kt^T /16, masked softmax -> P (bf16, LDS)
//  4) ctx = P V                       -> LDS
//  5) out = relu(Wu ctx^T + bu)       (fp32, channels-first)
__global__ __launch_bounds__(512, 2) void mega_kernel(
    const float* __restrict__ X,
    const unsigned short* __restrict__ W1, const float* __restrict__ b1,
    const unsigned short* __restrict__ W2, const float* __restrict__ b2,
    const unsigned short* __restrict__ Kt, const unsigned short* __restrict__ Vv,
    const unsigned short* __restrict__ Wu, const float* __restrict__ bu,
    float* __restrict__ Out) {
  const int HW = 16384;
  __shared__ __align__(16) char smem[131072];
  char* q2s = smem + 65536;       // q2 / ctx region; first 32KB doubles as xs
  float* xs = (float*)q2s;

  const int b = blockIdx.y;
  const int p0 = blockIdx.x * 128;
  const int tid = (int)threadIdx.x;
  const int wid = tid >> 6, l = tid & 63;
  const int lr = l & 15, lg = (l >> 4) & 3;
  const f32x4 zero = {0.f, 0.f, 0.f, 0.f};

  // ---- Phase 1: q1s = relu(x^T @ W1^T + b1), fused transpose ----
  {
    const int pbase = (wid >> 1) * 32, cbase = (wid & 1) * 128;
    const float* Xb = X + (size_t)b * 512 * HW + p0;
    f32x4 acc[2][8];
#pragma unroll
    for (int m = 0; m < 2; m++)
#pragma unroll
      for (int n = 0; n < 8; n++) acc[m][n] = zero;
    const int arow = l >> 5, acol = l & 31;
#pragma unroll 1
    for (int kt = 0; kt < 512; kt += 64) {
      __syncthreads();
#pragma unroll
      for (int i = 0; i < 4; i++) {
        const int rk = wid * 8 + i * 2 + arow;     // s = rk>>3 = wid
        __builtin_amdgcn_global_load_lds(
            (AS1 void*)(Xb + (size_t)(kt + rk) * HW + ((acol ^ wid) << 2)),
            (AS3 void*)(xs + (wid * 8 + i * 2) * 128), 16, 0, 0);
      }
      __syncthreads();
#pragma unroll
      for (int ks = 0; ks < 2; ks++) {
        const int s = ks * 4 + lg;                 // (rk>>3) for frag rows
        bf16x8 aF[2];
#pragma unroll
        for (int m = 0; m < 2; m++) {
          const int p = pbase + m * 16 + lr;
          const int cb = (((p >> 2) ^ s) << 2) | (p & 3);
          bf16x8 a;
#pragma unroll
          for (int j = 0; j < 8; j++)
            a[j] = (__bf16)xs[(ks * 32 + lg * 8 + j) * 128 + cb];
          aF[m] = a;
        }
#pragma unroll
        for (int n = 0; n < 8; n++) {
          bf16x8 bF = *(const bf16x8*)(W1 + (size_t)(cbase + n * 16 + lr) * 512 +
                                       kt + ks * 32 + lg * 8);
          acc[0][n] = MFMA_16x16x32(aF[0], bF, acc[0][n]);
          acc[1][n] = MFMA_16x16x32(aF[1], bF, acc[1][n]);
        }
      }
    }
    // q1 -> q1s (smem[0:64K)), swizzled u16 scatter
#pragma unroll
    for (int n = 0; n < 8; n++) {
      const int ch = cbase + n * 16 + lr;
      const float bb = b1[ch];
#pragma unroll
      for (int m = 0; m < 2; m++)
#pragma unroll
        for (int r = 0; r < 4; r++) {
          const int pix = pbase + m * 16 + lg * 4 + r;
          const unsigned boff =
              ((unsigned)pix * 512 + (unsigned)ch * 2) ^ (((unsigned)pix & 7u) << 4);
          *(unsigned short*)(smem + boff) = f2bf(fmaxf(acc[m][n][r] + bb, 0.f));
        }
    }
  }
  __syncthreads();

  // ---- Phase 2: q2s = relu(q1 @ W2^T + b2) ----
  {
    const int pbase = (wid >> 1) * 32, cbase = (wid & 1) * 128;
    f32x4 acc[2][8];
#pragma unroll
    for (int m = 0; m < 2; m++)
#pragma unroll
      for (int n = 0; n < 8; n++) acc[m][n] = zero;
#pragma unroll
    for (int ks = 0; ks < 8; ks++) {
      bf16x8 aF[2];
#pragma unroll
      for (int m = 0; m < 2; m++) {
        const int p = pbase + m * 16 + lr;
        const unsigned boff = ((unsigned)p * 512 + (unsigned)(ks * 64 + lg * 16)) ^
                              (((unsigned)p & 7u) << 4);
        aF[m] = *(const bf16x8*)(smem + boff);
      }
#pragma unroll
      for (int n = 0; n < 8; n++) {
        bf16x8 bF = *(const bf16x8*)(W2 + (size_t)(cbase + n * 16 + lr) * 256 +
                                     ks * 32 + lg * 8);
        acc[0][n] = MFMA_16x16x32(aF[0], bF, acc[0][n]);
        acc[1][n] = MFMA_16x16x32(aF[1], bF, acc[1][n]);
      }
    }
#pragma unroll
    for (int n = 0; n < 8; n++) {
      const int ch = cbase + n * 16 + lr;
      const float bb = b2[ch];
#pragma unroll
      for (int m = 0; m < 2; m++)
#pragma unroll
        for (int r = 0; r < 4; r++) {
          const int pix = pbase + m * 16 + lg * 4 + r;
          const unsigned boff =
              ((unsigned)pix * 512 + (unsigned)ch * 2) ^ (((unsigned)pix & 7u) << 4);
          *(unsigned short*)(q2s + boff) = f2bf(fmaxf(acc[m][n][r] + bb, 0.f));
        }
    }
  }
  __syncthreads();

  // ---- Phase 3: S = q2 Kt^T /16, masked softmax -> P (q1s region) ----
  {
    const unsigned short* Kb = Kt + (size_t)b * 160 * 256;
    const int pbase = wid * 16;
    f32x4 acc[10];
#pragma unroll
    for (int n = 0; n < 10; n++) acc[n] = zero;
#pragma unroll
    for (int ks = 0; ks < 8; ks++) {
      const int p = pbase + lr;
      const unsigned boff = ((unsigned)p * 512 + (unsigned)(ks * 64 + lg * 16)) ^
                            (((unsigned)p & 7u) << 4);
      bf16x8 aF = *(const bf16x8*)(q2s + boff);
#pragma unroll
      for (int n = 0; n < 10; n++) {
        bf16x8 bF = *(const bf16x8*)(Kb + (size_t)(n * 16 + lr) * 256 + ks * 32 + lg * 8);
        acc[n] = MFMA_16x16x32(aF, bF, acc[n]);
      }
    }
    const float scale = 0.0625f;  // 1/sqrt(256)
#pragma unroll
    for (int r = 0; r < 4; r++) {
      float lm = -1e30f;
#pragma unroll
      for (int n = 0; n < 10; n++) {
        float v = acc[n][r] * scale;
        acc[n][r] = v;
        if (n * 16 + lr < 150) lm = fmaxf(lm, v);
      }
#pragma unroll
      for (int msk = 1; msk <= 8; msk <<= 1) lm = fmaxf(lm, __shfl_xor(lm, msk, 64));
      float s = 0.f;
#pragma unroll
      for (int n = 0; n < 10; n++) {
        float p = (n * 16 + lr < 150) ? __expf(acc[n][r] - lm) : 0.f;
        acc[n][r] = p;
        s += p;
      }
#pragma unroll
      for (int msk = 1; msk <= 8; msk <<= 1) s += __shfl_xor(s, msk, 64);
      float inv = 1.f / s;
      const int row = pbase + lg * 4 + r;
      const unsigned sw = (((unsigned)row & 7u) << 4);
#pragma unroll
      for (int n = 0; n < 10; n++) {
        const unsigned boff = ((unsigned)row * 320 + (unsigned)(n * 16 + lr) * 2) ^ sw;
        *(unsigned short*)(smem + boff) = f2bf(acc[n][r] * inv);
      }
    }
  }
  __syncthreads();

  // ---- Phase 4: ctx = P @ V -> q2s (q2 dead) ----
  {
    const unsigned short* Vb = Vv + (size_t)b * 256 * 160;
    const int pbase = wid * 16;
    f32x4 acc[16];
#pragma unroll
    for (int n = 0; n < 16; n++) acc[n] = zero;
#pragma unroll
    for (int ks = 0; ks < 5; ks++) {
      const int p = pbase + lr;
      const unsigned boff = ((unsigned)p * 320 + (unsigned)(ks * 64 + lg * 16)) ^
                            (((unsigned)p & 7u) << 4);
      bf16x8 aF = *(const bf16x8*)(smem + boff);
#pragma unroll
      for (int n = 0; n < 16; n++) {
        bf16x8 bF = *(const bf16x8*)(Vb + (size_t)(n * 16 + lr) * 160 + ks * 32 + lg * 8);
        acc[n] = MFMA_16x16x32(aF, bF, acc[n]);
      }
    }
#pragma unroll
    for (int n = 0; n < 16; n++) {
#pragma unroll
      for (int r = 0; r < 4; r++) {
        const int pix = pbase + lg * 4 + r;
        const int ch = n * 16 + lr;
        const unsigned boff =
            ((unsigned)pix * 512 + (unsigned)ch * 2) ^ (((unsigned)pix & 7u) << 4);
        *(unsigned short*)(q2s + boff) = f2bf(acc[n][r]);
      }
    }
  }
  __syncthreads();

  // ---- Phase 5: out = relu(Wu @ ctx^T + bu), fp32, channels-first ----
  {
    float* Ob = Out + (size_t)b * 512 * HW + p0;
    const int cobase = wid * 64;
    f32x4 acc[4][8];
#pragma unroll
    for (int m = 0; m < 4; m++)
#pragma unroll
      for (int n = 0; n < 8; n++) acc[m][n] = zero;
#pragma unroll
    for (int ks = 0; ks < 8; ks++) {
      bf16x8 aF[4];
#pragma unroll
      for (int m = 0; m < 4; m++)
        aF[m] = *(const bf16x8*)(Wu + (size_t)(cobase + m * 16 + lr) * 256 +
                                 ks * 32 + lg * 8);
#pragma unroll
      for (int n = 0; n < 8; n++) {
        const int pix = n * 16 + lr;
        const unsigned boff = ((unsigned)pix * 512 + (unsigned)(ks * 64 + lg * 16)) ^
                              (((unsigned)pix & 7u) << 4);
        bf16x8 bF = *(const bf16x8*)(q2s + boff);
#pragma unroll
        for (int m = 0; m < 4; m++) acc[m][n] = MFMA_16x16x32(aF[m], bF, acc[m][n]);
      }
    }
#pragma unroll
    for (int m = 0; m < 4; m++) {
#pragma unroll
      for (int r = 0; r < 4; r++) {
        const int co = cobase + m * 16 + lg * 4 + r;
        const float bb = bu[co];
#pragma unroll
        for (int n = 0; n < 8; n++)
          Ob[(size_t)co * HW + n * 16 + lr] = fmaxf(acc[m][n][r] + bb, 0.f);
      }
    }
  }
}

// ---------------- host launcher ----------------
extern "C" void kernel_launch(void* const* d_in, const int* in_sizes, int n_in,
                              void* d_out, int out_size, void* d_ws, size_t ws_size,
                              hipStream_t stream) {
  (void)in_sizes; (void)n_in; (void)out_size;
  const float* x     = (const float*)d_in[0];
  const float* proxy = (const float*)d_in[1];
  const float* w_fp1 = (const float*)d_in[2];
  const float* b_fp1 = (const float*)d_in[3];
  const float* w_fp2 = (const float*)d_in[4];
  const float* b_fp2 = (const float*)d_in[5];
  const float* w_fo1 = (const float*)d_in[6];
  const float* b_fo1 = (const float*)d_in[7];
  const float* w_fo2 = (const float*)d_in[8];
  const float* b_fo2 = (const float*)d_in[9];
  const float* w_fd  = (const float*)d_in[10];
  const float* b_fd  = (const float*)d_in[11];
  const float* w_fu  = (const float*)d_in[12];
  const float* b_fu  = (const float*)d_in[13];

  char* ws = (char*)d_ws;
  unsigned short* W1b  = (unsigned short*)(ws + 0);          // 256x512 bf16
  unsigned short* W2b  = (unsigned short*)(ws + 262144);     // 256x256
  unsigned short* Wub  = (unsigned short*)(ws + 393216);     // 512x256
  unsigned short* keyT = (unsigned short*)(ws + 655360);     // [8][160][256]
  unsigned short* Vv   = (unsigned short*)(ws + 1310720);    // [8][256][160]
  if (ws_size < 2097152) return;

  dim3 blk(256);
  cast_weights<<<1280, blk, 0, stream>>>(w_fp1, w_fp2, w_fu, W1b, W2b, Wub);
  kv_kernel<<<dim3(20, 8), blk, 0, stream>>>(proxy, w_fo1, b_fo1, w_fo2, b_fo2,
                                             w_fd, b_fd, keyT, Vv);
  mega_kernel<<<dim3(128, 8), dim3(512), 0, stream>>>(
      x, W1b, b_fp1, W2b, b_fp2, keyT, Vv, Wub, b_fu, (float*)d_out);
}